// Round 19
// baseline (208.999 us; speedup 1.0000x reference)
//
#include <hip/hip_runtime.h>
#include <cstddef>

// CS=8 NV=4 ED=32 VIEWS=3 D=16 KSZ=3 HW=14 CSP=8 KSTATES=4096
// Pipeline (3 launches) — r17 pmat/prep + DOUBLE-BUFFERED fused:
//   pmat: P3[v][33][4096] once (row 32 = lin_b), lin_w read once.
//   prep: blocks 0..197 = fold role (P3 half -> conv_t1 -> Qa/Qb)
//         blocks 198..215 = pre roles (xB frags, x2, Wf)
//   fusedgemm per (16-state tile, view), 256 thr: sH1/sH2 double-buffered
//     by state parity -> ONE barrier per state (was 2):
//     interval = [ph2(s) ; ph1(s+1) ; ph3(s-1)] barrier — all disjoint bufs.
//     LDS 76.8 KB -> 2 blocks/CU (trade concurrency for 2x fewer barriers).

typedef __attribute__((ext_vector_type(4))) float f32x4;
typedef _Float16 half8v __attribute__((ext_vector_type(8)));
typedef _Float16 half4v __attribute__((ext_vector_type(4)));
typedef _Float16 half2v __attribute__((ext_vector_type(2)));

static __device__ __forceinline__ float elu(float s) {
    float e = __expf(s) - 1.0f;
    return s > 0.f ? s : e;
}
static __device__ __forceinline__ float dot2acc(int hpair, int wpair, float acc) {
#if __has_builtin(__builtin_amdgcn_fdot2)
    return __builtin_amdgcn_fdot2(__builtin_bit_cast(half2v, hpair),
                                  __builtin_bit_cast(half2v, wpair), acc, false);
#else
    half2v h = __builtin_bit_cast(half2v, hpair);
    half2v w = __builtin_bit_cast(half2v, wpair);
    acc = fmaf((float)h.x, (float)w.x, acc);
    return fmaf((float)h.y, (float)w.y, acc);
#endif
}
static __device__ __forceinline__ int sh2addr(int c, int r) {
    return c * 392 + r * 24 + (((r >> 2) & 3) << 3);
}

// ---------------- pmat: P3[v][vc][o], lin_w read once ----------------
__global__ __launch_bounds__(256) void pmat_kernel(const float* __restrict__ le,
                                                   const float* __restrict__ lin_w,
                                                   const float* __restrict__ lin_b,
                                                   float* __restrict__ P3) {
    int o = blockIdx.x * 256 + threadIdx.x;   // 0..4095
    int y = blockIdx.y;                        // 0..3 = vp, 4 = bias row
    int v = blockIdx.z;
    if (y == 4) {
        P3[((size_t)v * 33 + 32) * 4096 + o] = lin_b[v * 4096 + o];
        return;
    }
    int vp = y;
    const float* lwv = lin_w + (size_t)v * 524288 + (size_t)vp * 131072 + o;
    float acc[8];
#pragma unroll
    for (int j = 0; j < 8; ++j) acc[j] = 0.f;
    const float* lep = le + vp * 8 * 32;
    for (int e = 0; e < 32; ++e) {
        float lw = lwv[e * 4096];
#pragma unroll
        for (int j = 0; j < 8; ++j)
            acc[j] = fmaf(lep[j * 32 + e], lw, acc[j]);
    }
#pragma unroll
    for (int j = 0; j < 8; ++j)
        P3[((size_t)v * 33 + vp * 8 + j) * 4096 + o] = acc[j];
}

// ---------------- prep: fold roles (0..197) + pre roles (198..215) — r17 form ----------------
__global__ __launch_bounds__(320) void prep_kernel(const float* __restrict__ x,
                                                   const float* __restrict__ P3,
                                                   const float* __restrict__ w1,
                                                   const float* __restrict__ b1,
                                                   const float* __restrict__ w2,
                                                   float* __restrict__ Qa,
                                                   float* __restrict__ Qb,
                                                   float* __restrict__ x2,
                                                   short* __restrict__ xB,
                                                   short* __restrict__ Wf) {
    int bid = blockIdx.x;
    int t = threadIdx.x;
    if (bid >= 198) {
        int pid = bid - 198;
        int v = pid % 3, part = pid / 3;
        if (part < 4) {
            int nb = part;
            short* xBv = xB + v * 14336 + nb * 3584;
            for (int idx = t; idx < 3584; idx += 320) {
                int j = idx & 7, lane = (idx >> 3) & 63, s = idx >> 9;
                int px = s * 32 + ((lane >> 4) << 3) + j;
                int b  = nb * 16 + (lane & 15);
                float val = (px < 196) ? x[(b * 3 + v) * 196 + px] : 0.f;
                _Float16 h = (_Float16)val;
                xBv[idx] = __builtin_bit_cast(short, h);
            }
        } else if (part == 4) {
            int w = t >> 6, lane = t & 63;
            for (int b = w; b < 64; b += 5) {
                const float* xp = x + (b * 3 + v) * 196;
                float s = 0.f;
                for (int px = lane; px < 196; px += 64) s = fmaf(xp[px], xp[px], s);
#pragma unroll
                for (int off = 32; off; off >>= 1) s += __shfl_down(s, off, 64);
                if (lane == 0) x2[v * 64 + b] = s;
            }
        } else if (t < 64) {
            int lane = t;
            const float* w2v = w2 + v * 32 * 16 * 9;
            int co = lane & 15;
            int cibase = (lane >> 4) * 8;
#pragma unroll
            for (int tap = 0; tap < 9; ++tap)
#pragma unroll
                for (int j = 0; j < 8; ++j) {
                    _Float16 h = (_Float16)w2v[((cibase + j) * 16 + co) * 9 + tap];
                    Wf[(((v * 9 + tap) * 64 + lane) << 3) + j] = __builtin_bit_cast(short, h);
                }
        }
        return;
    }
    // ---- fold role: (row, v, z) — reads its 8KB P3 half from L2 ----
    __shared__ float sPt[32 * 144];     // [ci_local][x_pad 12][y_pad 12], zero-padded
    __shared__ float sW[16 * 32 * 9];
    int row = bid % 33;
    int v   = (bid / 33) % 3;
    int z   = bid / 99;

    const float* src = P3 + ((size_t)v * 33 + row) * 4096 + z * 2048;
    float4* zp = (float4*)sPt;
    for (int i = t; i < 1152; i += 320) zp[i] = float4{0.f, 0.f, 0.f, 0.f};
    __syncthreads();
    for (int i = t; i < 2048; i += 320) {
        int ci = i >> 6, r = i & 63, y = r >> 3, xx = r & 7;
        sPt[ci * 144 + (xx + 2) * 12 + (y + 2)] = src[i];
    }
    const float* w1v = w1 + (size_t)v * 18432;
    int co = t / 10, ox = t % 10;
    float acc[10];
#pragma unroll
    for (int i = 0; i < 10; ++i) acc[i] = 0.f;

    for (int c0l = 0; c0l < 2; ++c0l) {
        int c0 = z * 2 + c0l;
        __syncthreads();   // first pass also covers sPt fill
        const float4* wsrc = (const float4*)(w1v + c0 * 4608);
        for (int i = t; i < 1152; i += 320) ((float4*)sW)[i] = wsrc[i];
        __syncthreads();
#pragma unroll 2
        for (int ci = 0; ci < 16; ++ci) {
            const float* xp = sPt + (c0l * 16 + ci) * 144;
            const float* wp = sW + (ci * 32 + co) * 9;
            float wv[9];
#pragma unroll
            for (int j = 0; j < 9; ++j) wv[j] = wp[j];
#pragma unroll
            for (int b = 0; b < 3; ++b) {
                const float* colp = xp + (ox + 2 - b) * 12;
                float4 c0v = *(const float4*)(colp);
                float4 c1v = *(const float4*)(colp + 4);
                float4 c2v = *(const float4*)(colp + 8);
                float cv[12] = {c0v.x, c0v.y, c0v.z, c0v.w,
                                c1v.x, c1v.y, c1v.z, c1v.w,
                                c2v.x, c2v.y, c2v.z, c2v.w};
#pragma unroll
                for (int a = 0; a < 3; ++a) {
                    float wgt = wv[a * 3 + b];
#pragma unroll
                    for (int oy = 0; oy < 10; ++oy)
                        acc[oy] = fmaf(cv[oy + 2 - a], wgt, acc[oy]);
                }
            }
        }
    }
    float bb = (z == 0 && row == 32) ? b1[v * 32 + co] : 0.f;
    float* dst = (z == 0 ? Qa : Qb) + (size_t)v * 105600 + row * 3200;
#pragma unroll
    for (int oy = 0; oy < 10; ++oy)
        dst[(ox * 10 + oy) * 32 + co] = acc[oy] + bb;
}

// ---------------- fusedgemm: double-buffered, 1 barrier/state ----------------
__global__ __launch_bounds__(256) void fusedgemm_kernel(const float* __restrict__ Qa,    // [3][33][3200]
                                                        const float* __restrict__ Qb,    // [3][33][3200]
                                                        const short* __restrict__ Wf,    // [3][9][64][8]
                                                        const float* __restrict__ b2,
                                                        const float* __restrict__ w3,    // [3][16][9]
                                                        const float* __restrict__ b3,
                                                        const short* __restrict__ xB,    // [3][4][7][64][8]
                                                        const float* __restrict__ x2g,   // [3][64]
                                                        float* __restrict__ out) {       // [64][4096][3]
    __shared__ alignas(16) short sH1[2][7840];   // [pix=c*14+r][40 (32 used)] f16
    __shared__ alignas(16) short sH2[2][6280];   // swizzled: sh2addr(c,r)+co, f16
    __shared__ alignas(16) short sM[16 * 224];   // M rows for the 16 states, f16
    __shared__ alignas(16) float sQ[3200];       // staged digit sum (f32)
    __shared__ int sW3p[72];                     // [tap][ci-pair] packed half2
    __shared__ float sM2[16];
    int k0 = blockIdx.x * 16;
    int v = blockIdx.y;
    int t = threadIdx.x;
    int lane = t & 63;
    int g = lane >> 4;
    int w = t >> 6;

    half8v bfrag[9];
#pragma unroll
    for (int tap = 0; tap < 9; ++tap)
        bfrag[tap] = *(const half8v*)(const void*)(Wf + (((v * 9 + tap) * 64 + lane) << 3));
    float bias2 = b2[v * 16 + (lane & 15)];
    float bias3 = b3[v];

    if (t < 16) sM2[t] = 0.f;
    // zero pad regions of BOTH buffers once (interiors rewritten per state)
    for (int pix = t; pix < 196; pix += 256) {
        int c = pix / 14, r = pix % 14;
        if (c < 2 || c >= 12 || r < 2 || r >= 12) {
#pragma unroll
            for (int bi = 0; bi < 2; ++bi) {
                int4* z = (int4*)(sH1[bi] + pix * 40);
                z[0] = int4{0,0,0,0}; z[1] = int4{0,0,0,0};
                z[2] = int4{0,0,0,0}; z[3] = int4{0,0,0,0};
            }
        }
    }
    {
        int c = t >> 4, r = t & 15;
        if (c < 2 || c >= 14 || r < 2 || r >= 14) {
#pragma unroll
            for (int bi = 0; bi < 2; ++bi) {
                int4* z = (int4*)(sH2[bi] + sh2addr(c, r));
                z[0] = int4{0,0,0,0}; z[1] = int4{0,0,0,0};
            }
        }
    }
    if (t < 72) {
        int tap = t / 8, j = t % 8;
        half2v p = {(_Float16)w3[v * 144 + (2 * j) * 9 + tap],
                    (_Float16)w3[v * 144 + (2 * j + 1) * 9 + tap]};
        sW3p[t] = __builtin_bit_cast(int, p);
    }

    // ---- hoisted per-block address math ----
    int st1[4]; bool v1[4];
    {
        int ci4 = (t & 7) * 4;
#pragma unroll
        for (int j = 0; j < 4; ++j) {
            int i = t + j * 256;
            v1[j] = (i < 800);
            int pix = i >> 3;               // col*10 + row
            int cx = pix / 10, ry = pix % 10;
            st1[j] = ((cx + 2) * 14 + (ry + 2)) * 40 + ci4;
        }
    }
    int ntile = 0; int bmoff[3]; int soff[3][4];
    for (int tile = w; tile < 9; tile += 4) {
        int m = tile * 16 + (lane & 15);
        int cx2 = m / 12, ry2 = m % 12;
        bmoff[ntile] = (cx2 * 14 + ry2) * 40 + g * 8;
        int p0 = tile * 16 + g * 4;
        int cxp = p0 / 12, ryp = p0 % 12;
        int co = lane & 15;
#pragma unroll
        for (int r = 0; r < 4; ++r) {
            soff[ntile][r] = sh2addr(cxp + 2, ryp + 2) + co;
            ++ryp; if (ryp == 12) { ryp = 0; ++cxp; }
        }
        ++ntile;
    }
    // ph3: ROW-major lane mapping -> 12-bank lane stride
    int off3[9];
    int oidx = 0;
    {
        int ry3 = (t < 196) ? t % 14 : 0;
        int cx3 = (t < 196) ? t / 14 : 0;
        oidx = ry3 * 14 + cx3;
#pragma unroll
        for (int a = 0; a < 3; ++a)
#pragma unroll
            for (int b = 0; b < 3; ++b)
                off3[a * 3 + b] = sh2addr(cx3 + 2 - b, ry3 + 2 - a);
    }

    // per-block digit indices
    const float* Qav = Qa + (size_t)v * 105600;
    const float* Qbv = Qb + (size_t)v * 105600;
    int i0 = (k0 >> 9) & 7;
    int i1 = (k0 >> 6) & 7;
    int i2b = (k0 >> 3) & 7;   // s<8 uses i2b, s>=8 uses i2b+1 (no wrap: k0 mult of 16)

    auto buildSQ = [&](int i2) {
        const float4* pa0 = (const float4*)(Qav + i0 * 3200);
        const float4* pb0 = (const float4*)(Qbv + i0 * 3200);
        const float4* pa1 = (const float4*)(Qav + (8 + i1) * 3200);
        const float4* pb1 = (const float4*)(Qbv + (8 + i1) * 3200);
        const float4* pa2 = (const float4*)(Qav + (16 + i2) * 3200);
        const float4* pb2 = (const float4*)(Qbv + (16 + i2) * 3200);
        const float4* pab = (const float4*)(Qav + 32 * 3200);
        const float4* pbb = (const float4*)(Qbv + 32 * 3200);
        float4* dq = (float4*)sQ;
        for (int i = t; i < 800; i += 256) {
            float4 A = pa0[i], B = pb0[i], C = pa1[i], D = pb1[i];
            float4 E = pa2[i], F = pb2[i], G = pab[i], H = pbb[i];
            dq[i] = float4{A.x + B.x + C.x + D.x + E.x + F.x + G.x + H.x,
                           A.y + B.y + C.y + D.y + E.y + F.y + G.y + H.y,
                           A.z + B.z + C.z + D.z + E.z + F.z + G.z + H.z,
                           A.w + B.w + C.w + D.w + E.w + F.w + G.w + H.w};
        }
    };
    auto doPh1 = [&](int s, short* h1dst) {
        int i3 = s & 7;
        const float4* qa3 = (const float4*)(Qav + (24 + i3) * 3200);
        const float4* qb3 = (const float4*)(Qbv + (24 + i3) * 3200);
        const float4* qs = (const float4*)sQ;
#pragma unroll
        for (int j = 0; j < 4; ++j) {
            if (v1[j]) {
                int i = t + j * 256;
                float4 q = qs[i], a = qa3[i], b = qb3[i];
                half4v o = {(_Float16)elu(q.x + a.x + b.x),
                            (_Float16)elu(q.y + a.y + b.y),
                            (_Float16)elu(q.z + a.z + b.z),
                            (_Float16)elu(q.w + a.w + b.w)};
                *(half4v*)(void*)(h1dst + st1[j]) = o;
            }
        }
    };
    auto doPh3 = [&](int sp, const short* h2src) {
        float mval = 0.f;
        if (t < 196) {
            float a0 = bias3, a1 = 0.f, a2 = 0.f, a3 = 0.f;
#pragma unroll
            for (int tap = 0; tap < 9; ++tap) {
                const short* base = h2src + off3[tap];
                int4 lo = *(const int4*)(const void*)(base);
                int4 hi = *(const int4*)(const void*)(base + 8);
                const int* wp = sW3p + tap * 8;
                a0 = dot2acc(lo.x, wp[0], a0);
                a1 = dot2acc(lo.y, wp[1], a1);
                a2 = dot2acc(lo.z, wp[2], a2);
                a3 = dot2acc(lo.w, wp[3], a3);
                a0 = dot2acc(hi.x, wp[4], a0);
                a1 = dot2acc(hi.y, wp[5], a1);
                a2 = dot2acc(hi.z, wp[6], a2);
                a3 = dot2acc(hi.w, wp[7], a3);
            }
            mval = (a0 + a1) + (a2 + a3);
            _Float16 h = (_Float16)mval;
            sM[sp * 224 + oidx] = __builtin_bit_cast(short, h);
        } else if (t < 224) {
            sM[sp * 224 + t] = 0;            // K-padding
        }
        float sq = mval * mval;
#pragma unroll
        for (int off = 32; off; off >>= 1) sq += __shfl_down(sq, off, 64);
        if (lane == 0) atomicAdd(&sM2[sp], sq);
    };

    buildSQ(i2b);
    __syncthreads();
    doPh1(0, sH1[0]);
    __syncthreads();

    for (int s = 0; s < 16; ++s) {
        // ph2(s): conv2 via MFMA f16 from sH1[s&1] -> sH2[s&1]
        {
            const short* h1cur = sH1[s & 1];
            short* h2cur = sH2[s & 1];
#pragma unroll
            for (int it = 0; it < 3; ++it) {
                if (it < ntile) {
                    const short* basemin = h1cur + bmoff[it];
                    f32x4 acc0 = {bias2, bias2, bias2, bias2};
                    f32x4 acc1 = {0.f, 0.f, 0.f, 0.f};
#pragma unroll
                    for (int a = 0; a < 3; ++a)
#pragma unroll
                        for (int b = 0; b < 3; ++b) {
                            half8v af = *(const half8v*)(const void*)(basemin + ((2 - b) * 14 + (2 - a)) * 40);
                            int idx = a * 3 + b;
                            if (idx & 1)
                                acc1 = __builtin_amdgcn_mfma_f32_16x16x32_f16(af, bfrag[idx], acc1, 0, 0, 0);
                            else
                                acc0 = __builtin_amdgcn_mfma_f32_16x16x32_f16(af, bfrag[idx], acc0, 0, 0, 0);
                        }
#pragma unroll
                    for (int r = 0; r < 4; ++r) {
                        _Float16 h = (_Float16)elu(acc0[r] + acc1[r]);
                        h2cur[soff[it][r]] = __builtin_bit_cast(short, h);
                    }
                }
            }
        }
        if (s < 15) {
            if (s == 7) {
                // old sQ last read by ph1(7) before the previous barrier
                buildSQ(i2b + 1);
                __syncthreads();     // new sQ visible before ph1(8)
            }
            doPh1(s + 1, sH1[(s + 1) & 1]);
        }
        if (s > 0) doPh3(s - 1, sH2[(s - 1) & 1]);
        __syncthreads();
    }
    doPh3(15, sH2[1]);
    __syncthreads();

    // ---- cross GEMM: C[k_local][b] = sum_px sM[k][px] * x[b][px] ----
    {
        f32x4 acc = {0.f, 0.f, 0.f, 0.f};
        const short* abase = sM + (lane & 15) * 224 + g * 8;
        const short* bbase = xB + (((v * 4 + w) * 7) * 64 + lane) * 8;
#pragma unroll
        for (int s7 = 0; s7 < 7; ++s7) {
            half8v af = *(const half8v*)(const void*)(abase + s7 * 32);
            half8v bf = *(const half8v*)(const void*)(bbase + s7 * 512);
            acc = __builtin_amdgcn_mfma_f32_16x16x32_f16(af, bf, acc, 0, 0, 0);
        }
        int b = w * 16 + (lane & 15);        // D col = lane&15 -> b-local
        float x2v = x2g[v * 64 + b];
        size_t obase = ((size_t)b * 4096 + k0) * 3 + v;
#pragma unroll
        for (int r = 0; r < 4; ++r) {
            int kk = g * 4 + r;              // D row -> k-local
            out[obase + (size_t)kk * 3] = acc[r] - 0.5f * (sM2[kk] + x2v);
        }
    }
}

extern "C" void kernel_launch(void* const* d_in, const int* in_sizes, int n_in,
                              void* d_out, int out_size, void* d_ws, size_t ws_size,
                              hipStream_t stream) {
    const float* x     = (const float*)d_in[0];
    const float* le    = (const float*)d_in[1];
    const float* lin_w = (const float*)d_in[2];
    const float* lin_b = (const float*)d_in[3];
    const float* w1    = (const float*)d_in[4];
    const float* b1    = (const float*)d_in[5];
    const float* w2    = (const float*)d_in[6];
    const float* b2    = (const float*)d_in[7];
    const float* w3    = (const float*)d_in[8];
    const float* b3    = (const float*)d_in[9];
    float* out = (float*)d_out;

    float* ws = (float*)d_ws;
    // workspace (floats):
    float* x2g  = ws;                        // 192
    short* xB   = (short*)(ws + 192);        // 43008 shorts = 21504 floats
    short* Wf   = (short*)(ws + 21760);      // 13824 shorts = 6912 floats
    float* Qa   = ws + 28736;                // 316800
    float* Qb   = ws + 345536;               // 316800
    float* P3   = ws + 662336;               // 3*33*4096 = 405504

    pmat_kernel<<<dim3(16, 5, 3), 256, 0, stream>>>(le, lin_w, lin_b, P3);
    prep_kernel<<<216, 320, 0, stream>>>(x, P3, w1, b1, w2, Qa, Qb, x2g, xB, Wf);
    fusedgemm_kernel<<<dim3(256, 3), 256, 0, stream>>>(Qa, Qb, Wf, b2, w3, b3,
                                                       xB, x2g, out);
}

// Round 20
// 169.455 us; speedup vs baseline: 1.2334x; 1.2334x over previous
//
#include <hip/hip_runtime.h>
#include <cstddef>

// CS=8 NV=4 ED=32 VIEWS=3 D=16 KSZ=3 HW=14 CSP=8 KSTATES=4096
// FINAL (r17 config — best measured 170.8 µs):
//   pmat: P3[v][33][4096] once (row 32 = lin_b), lin_w read once.
//   prep: blocks 0..197 = fold role (P3 half -> conv_t1 -> Qa/Qb)
//         blocks 198..215 = pre roles (xB frags, x2, Wf)
//   fusedgemm per (16-state tile, view), 256 thr: sQ LDS digit sums;
//     ph1 ELU -> f16 sH1; ph2 conv2 = 81x mfma f16; ph3 conv3(dot2,
//     row-major lanes) -> sM + m2; cross GEMM sM x xB -> out.
// Tuning ledger (all measured):
//   16-state/48.6KB/2-barriers = optimum; 8-state(r16) +2us; reg-qsum(r14)
//   +39us; dbuf(r19) +36us; conflicts swizzles: counter -11%, time flat.

typedef __attribute__((ext_vector_type(4))) float f32x4;
typedef _Float16 half8v __attribute__((ext_vector_type(8)));
typedef _Float16 half4v __attribute__((ext_vector_type(4)));
typedef _Float16 half2v __attribute__((ext_vector_type(2)));

static __device__ __forceinline__ float elu(float s) {
    float e = __expf(s) - 1.0f;
    return s > 0.f ? s : e;
}
static __device__ __forceinline__ float dot2acc(int hpair, int wpair, float acc) {
#if __has_builtin(__builtin_amdgcn_fdot2)
    return __builtin_amdgcn_fdot2(__builtin_bit_cast(half2v, hpair),
                                  __builtin_bit_cast(half2v, wpair), acc, false);
#else
    half2v h = __builtin_bit_cast(half2v, hpair);
    half2v w = __builtin_bit_cast(half2v, wpair);
    acc = fmaf((float)h.x, (float)w.x, acc);
    return fmaf((float)h.y, (float)w.y, acc);
#endif
}
static __device__ __forceinline__ int sh2addr(int c, int r) {
    return c * 392 + r * 24 + (((r >> 2) & 3) << 3);
}

// ---------------- pmat: P3[v][vc][o], lin_w read once ----------------
__global__ __launch_bounds__(256) void pmat_kernel(const float* __restrict__ le,
                                                   const float* __restrict__ lin_w,
                                                   const float* __restrict__ lin_b,
                                                   float* __restrict__ P3) {
    int o = blockIdx.x * 256 + threadIdx.x;   // 0..4095
    int y = blockIdx.y;                        // 0..3 = vp, 4 = bias row
    int v = blockIdx.z;
    if (y == 4) {
        P3[((size_t)v * 33 + 32) * 4096 + o] = lin_b[v * 4096 + o];
        return;
    }
    int vp = y;
    const float* lwv = lin_w + (size_t)v * 524288 + (size_t)vp * 131072 + o;
    float acc[8];
#pragma unroll
    for (int j = 0; j < 8; ++j) acc[j] = 0.f;
    const float* lep = le + vp * 8 * 32;
    for (int e = 0; e < 32; ++e) {
        float lw = lwv[e * 4096];
#pragma unroll
        for (int j = 0; j < 8; ++j)
            acc[j] = fmaf(lep[j * 32 + e], lw, acc[j]);
    }
#pragma unroll
    for (int j = 0; j < 8; ++j)
        P3[((size_t)v * 33 + vp * 8 + j) * 4096 + o] = acc[j];
}

// ---------------- prep: fold roles (0..197) + pre roles (198..215) ----------------
__global__ __launch_bounds__(320) void prep_kernel(const float* __restrict__ x,
                                                   const float* __restrict__ P3,
                                                   const float* __restrict__ w1,
                                                   const float* __restrict__ b1,
                                                   const float* __restrict__ w2,
                                                   float* __restrict__ Qa,
                                                   float* __restrict__ Qb,
                                                   float* __restrict__ x2,
                                                   short* __restrict__ xB,
                                                   short* __restrict__ Wf) {
    int bid = blockIdx.x;
    int t = threadIdx.x;
    if (bid >= 198) {
        int pid = bid - 198;
        int v = pid % 3, part = pid / 3;
        if (part < 4) {
            int nb = part;
            short* xBv = xB + v * 14336 + nb * 3584;
            for (int idx = t; idx < 3584; idx += 320) {
                int j = idx & 7, lane = (idx >> 3) & 63, s = idx >> 9;
                int px = s * 32 + ((lane >> 4) << 3) + j;
                int b  = nb * 16 + (lane & 15);
                float val = (px < 196) ? x[(b * 3 + v) * 196 + px] : 0.f;
                _Float16 h = (_Float16)val;
                xBv[idx] = __builtin_bit_cast(short, h);
            }
        } else if (part == 4) {
            int w = t >> 6, lane = t & 63;
            for (int b = w; b < 64; b += 5) {
                const float* xp = x + (b * 3 + v) * 196;
                float s = 0.f;
                for (int px = lane; px < 196; px += 64) s = fmaf(xp[px], xp[px], s);
#pragma unroll
                for (int off = 32; off; off >>= 1) s += __shfl_down(s, off, 64);
                if (lane == 0) x2[v * 64 + b] = s;
            }
        } else if (t < 64) {
            int lane = t;
            const float* w2v = w2 + v * 32 * 16 * 9;
            int co = lane & 15;
            int cibase = (lane >> 4) * 8;
#pragma unroll
            for (int tap = 0; tap < 9; ++tap)
#pragma unroll
                for (int j = 0; j < 8; ++j) {
                    _Float16 h = (_Float16)w2v[((cibase + j) * 16 + co) * 9 + tap];
                    Wf[(((v * 9 + tap) * 64 + lane) << 3) + j] = __builtin_bit_cast(short, h);
                }
        }
        return;
    }
    // ---- fold role: (row, v, z) — reads its 8KB P3 half from L2 ----
    __shared__ float sPt[32 * 144];     // [ci_local][x_pad 12][y_pad 12], zero-padded
    __shared__ float sW[16 * 32 * 9];
    int row = bid % 33;
    int v   = (bid / 33) % 3;
    int z   = bid / 99;

    const float* src = P3 + ((size_t)v * 33 + row) * 4096 + z * 2048;
    float4* zp = (float4*)sPt;
    for (int i = t; i < 1152; i += 320) zp[i] = float4{0.f, 0.f, 0.f, 0.f};
    __syncthreads();
    for (int i = t; i < 2048; i += 320) {
        int ci = i >> 6, r = i & 63, y = r >> 3, xx = r & 7;
        sPt[ci * 144 + (xx + 2) * 12 + (y + 2)] = src[i];
    }
    const float* w1v = w1 + (size_t)v * 18432;
    int co = t / 10, ox = t % 10;
    float acc[10];
#pragma unroll
    for (int i = 0; i < 10; ++i) acc[i] = 0.f;

    for (int c0l = 0; c0l < 2; ++c0l) {
        int c0 = z * 2 + c0l;
        __syncthreads();   // first pass also covers sPt fill
        const float4* wsrc = (const float4*)(w1v + c0 * 4608);
        for (int i = t; i < 1152; i += 320) ((float4*)sW)[i] = wsrc[i];
        __syncthreads();
#pragma unroll 2
        for (int ci = 0; ci < 16; ++ci) {
            const float* xp = sPt + (c0l * 16 + ci) * 144;
            const float* wp = sW + (ci * 32 + co) * 9;
            float wv[9];
#pragma unroll
            for (int j = 0; j < 9; ++j) wv[j] = wp[j];
#pragma unroll
            for (int b = 0; b < 3; ++b) {
                const float* colp = xp + (ox + 2 - b) * 12;
                float4 c0v = *(const float4*)(colp);
                float4 c1v = *(const float4*)(colp + 4);
                float4 c2v = *(const float4*)(colp + 8);
                float cv[12] = {c0v.x, c0v.y, c0v.z, c0v.w,
                                c1v.x, c1v.y, c1v.z, c1v.w,
                                c2v.x, c2v.y, c2v.z, c2v.w};
#pragma unroll
                for (int a = 0; a < 3; ++a) {
                    float wgt = wv[a * 3 + b];
#pragma unroll
                    for (int oy = 0; oy < 10; ++oy)
                        acc[oy] = fmaf(cv[oy + 2 - a], wgt, acc[oy]);
                }
            }
        }
    }
    float bb = (z == 0 && row == 32) ? b1[v * 32 + co] : 0.f;
    float* dst = (z == 0 ? Qa : Qb) + (size_t)v * 105600 + row * 3200;
#pragma unroll
    for (int oy = 0; oy < 10; ++oy)
        dst[(ox * 10 + oy) * 32 + co] = acc[oy] + bb;
}

// ---------------- fusedgemm: sQ LDS + 16 states + cross GEMM ----------------
__global__ __launch_bounds__(256) void fusedgemm_kernel(const float* __restrict__ Qa,    // [3][33][3200]
                                                        const float* __restrict__ Qb,    // [3][33][3200]
                                                        const short* __restrict__ Wf,    // [3][9][64][8]
                                                        const float* __restrict__ b2,
                                                        const float* __restrict__ w3,    // [3][16][9]
                                                        const float* __restrict__ b3,
                                                        const short* __restrict__ xB,    // [3][4][7][64][8]
                                                        const float* __restrict__ x2g,   // [3][64]
                                                        float* __restrict__ out) {       // [64][4096][3]
    __shared__ alignas(16) short sH1[196 * 40];  // [pix=c*14+r][40 (32 used)] f16
    __shared__ alignas(16) short sH2[6280];      // swizzled: sh2addr(c,r)+co, f16
    __shared__ alignas(16) short sM[16 * 224];   // M rows for the 16 states, f16
    __shared__ alignas(16) float sQ[3200];       // staged digit sum (f32)
    __shared__ int sW3p[72];                     // [tap][ci-pair] packed half2
    __shared__ float sM2[16];
    int k0 = blockIdx.x * 16;
    int v = blockIdx.y;
    int t = threadIdx.x;
    int lane = t & 63;
    int g = lane >> 4;
    int w = t >> 6;

    half8v bfrag[9];
#pragma unroll
    for (int tap = 0; tap < 9; ++tap)
        bfrag[tap] = *(const half8v*)(const void*)(Wf + (((v * 9 + tap) * 64 + lane) << 3));
    float bias2 = b2[v * 16 + (lane & 15)];
    float bias3 = b3[v];

    if (t < 16) sM2[t] = 0.f;
    for (int pix = t; pix < 196; pix += 256) {
        int c = pix / 14, r = pix % 14;
        if (c < 2 || c >= 12 || r < 2 || r >= 12) {
            int4* z = (int4*)(sH1 + pix * 40);
            z[0] = int4{0,0,0,0}; z[1] = int4{0,0,0,0};
            z[2] = int4{0,0,0,0}; z[3] = int4{0,0,0,0};
        }
    }
    {
        int c = t >> 4, r = t & 15;
        if (c < 2 || c >= 14 || r < 2 || r >= 14) {
            int4* z = (int4*)(sH2 + sh2addr(c, r));
            z[0] = int4{0,0,0,0}; z[1] = int4{0,0,0,0};
        }
    }
    if (t < 72) {
        int tap = t / 8, j = t % 8;
        half2v p = {(_Float16)w3[v * 144 + (2 * j) * 9 + tap],
                    (_Float16)w3[v * 144 + (2 * j + 1) * 9 + tap]};
        sW3p[t] = __builtin_bit_cast(int, p);
    }

    // ---- hoisted per-block address math ----
    int st1[4]; bool v1[4];
    {
        int ci4 = (t & 7) * 4;
#pragma unroll
        for (int j = 0; j < 4; ++j) {
            int i = t + j * 256;
            v1[j] = (i < 800);
            int pix = i >> 3;               // col*10 + row
            int cx = pix / 10, ry = pix % 10;
            st1[j] = ((cx + 2) * 14 + (ry + 2)) * 40 + ci4;
        }
    }
    int ntile = 0; int bmoff[3]; int soff[3][4];
    for (int tile = w; tile < 9; tile += 4) {
        int m = tile * 16 + (lane & 15);
        int cx2 = m / 12, ry2 = m % 12;
        bmoff[ntile] = (cx2 * 14 + ry2) * 40 + g * 8;
        int p0 = tile * 16 + g * 4;
        int cxp = p0 / 12, ryp = p0 % 12;
        int co = lane & 15;
#pragma unroll
        for (int r = 0; r < 4; ++r) {
            soff[ntile][r] = sh2addr(cxp + 2, ryp + 2) + co;
            ++ryp; if (ryp == 12) { ryp = 0; ++cxp; }
        }
        ++ntile;
    }
    // ph3: ROW-major lane mapping -> 12-bank lane stride
    int off3[9];
    int oidx = 0;
    {
        int ry3 = (t < 196) ? t % 14 : 0;
        int cx3 = (t < 196) ? t / 14 : 0;
        oidx = ry3 * 14 + cx3;
#pragma unroll
        for (int a = 0; a < 3; ++a)
#pragma unroll
            for (int b = 0; b < 3; ++b)
                off3[a * 3 + b] = sh2addr(cx3 + 2 - b, ry3 + 2 - a);
    }

    // per-block digit indices
    const float* Qav = Qa + (size_t)v * 105600;
    const float* Qbv = Qb + (size_t)v * 105600;
    int i0 = (k0 >> 9) & 7;
    int i1 = (k0 >> 6) & 7;
    int i2b = (k0 >> 3) & 7;   // s<8 uses i2b, s>=8 uses i2b+1 (no wrap: k0 mult of 16)

    for (int s = 0; s < 16; ++s) {
        // rebuild sQ at s=0 and s=8 (i2 flips)
        if ((s & 7) == 0) {
            int i2 = i2b + (s >> 3);
            const float4* pa0 = (const float4*)(Qav + i0 * 3200);
            const float4* pb0 = (const float4*)(Qbv + i0 * 3200);
            const float4* pa1 = (const float4*)(Qav + (8 + i1) * 3200);
            const float4* pb1 = (const float4*)(Qbv + (8 + i1) * 3200);
            const float4* pa2 = (const float4*)(Qav + (16 + i2) * 3200);
            const float4* pb2 = (const float4*)(Qbv + (16 + i2) * 3200);
            const float4* pab = (const float4*)(Qav + 32 * 3200);
            const float4* pbb = (const float4*)(Qbv + 32 * 3200);
            float4* dq = (float4*)sQ;
            for (int i = t; i < 800; i += 256) {
                float4 A = pa0[i], B = pb0[i], C = pa1[i], D = pb1[i];
                float4 E = pa2[i], F = pb2[i], G = pab[i], H = pbb[i];
                dq[i] = float4{A.x + B.x + C.x + D.x + E.x + F.x + G.x + H.x,
                               A.y + B.y + C.y + D.y + E.y + F.y + G.y + H.y,
                               A.z + B.z + C.z + D.z + E.z + F.z + G.z + H.z,
                               A.w + B.w + C.w + D.w + E.w + F.w + G.w + H.w};
            }
            __syncthreads();
        }
        // ph1: h1 = ELU(sQ + Qa[24+i3] + Qb[24+i3]) -> sH1 (f16)
        {
            int i3 = s & 7;
            const float4* qa3 = (const float4*)(Qav + (24 + i3) * 3200);
            const float4* qb3 = (const float4*)(Qbv + (24 + i3) * 3200);
            const float4* qs = (const float4*)sQ;
#pragma unroll
            for (int j = 0; j < 4; ++j) {
                if (v1[j]) {
                    int i = t + j * 256;
                    float4 q = qs[i], a = qa3[i], b = qb3[i];
                    half4v o = {(_Float16)elu(q.x + a.x + b.x),
                                (_Float16)elu(q.y + a.y + b.y),
                                (_Float16)elu(q.z + a.z + b.z),
                                (_Float16)elu(q.w + a.w + b.w)};
                    *(half4v*)(void*)(sH1 + st1[j]) = o;
                }
            }
        }
        __syncthreads();
        // ph2: conv2 via MFMA f16, dual accumulators
#pragma unroll
        for (int it = 0; it < 3; ++it) {
            if (it < ntile) {
                const short* basemin = sH1 + bmoff[it];
                f32x4 acc0 = {bias2, bias2, bias2, bias2};
                f32x4 acc1 = {0.f, 0.f, 0.f, 0.f};
#pragma unroll
                for (int a = 0; a < 3; ++a)
#pragma unroll
                    for (int b = 0; b < 3; ++b) {
                        half8v af = *(const half8v*)(const void*)(basemin + ((2 - b) * 14 + (2 - a)) * 40);
                        int idx = a * 3 + b;
                        if (idx & 1)
                            acc1 = __builtin_amdgcn_mfma_f32_16x16x32_f16(af, bfrag[idx], acc1, 0, 0, 0);
                        else
                            acc0 = __builtin_amdgcn_mfma_f32_16x16x32_f16(af, bfrag[idx], acc0, 0, 0, 0);
                    }
#pragma unroll
                for (int r = 0; r < 4; ++r) {
                    _Float16 h = (_Float16)elu(acc0[r] + acc1[r]);
                    sH2[soff[it][r]] = __builtin_bit_cast(short, h);
                }
            }
        }
        __syncthreads();
        // ph3: conv3 via v_dot2_f32_f16 (row-major lanes) -> sM row + m2
        {
            float mval = 0.f;
            if (t < 196) {
                float a0 = bias3, a1 = 0.f, a2 = 0.f, a3 = 0.f;
#pragma unroll
                for (int tap = 0; tap < 9; ++tap) {
                    const short* base = sH2 + off3[tap];
                    int4 lo = *(const int4*)(const void*)(base);
                    int4 hi = *(const int4*)(const void*)(base + 8);
                    const int* wp = sW3p + tap * 8;
                    a0 = dot2acc(lo.x, wp[0], a0);
                    a1 = dot2acc(lo.y, wp[1], a1);
                    a2 = dot2acc(lo.z, wp[2], a2);
                    a3 = dot2acc(lo.w, wp[3], a3);
                    a0 = dot2acc(hi.x, wp[4], a0);
                    a1 = dot2acc(hi.y, wp[5], a1);
                    a2 = dot2acc(hi.z, wp[6], a2);
                    a3 = dot2acc(hi.w, wp[7], a3);
                }
                mval = (a0 + a1) + (a2 + a3);
                _Float16 h = (_Float16)mval;
                sM[s * 224 + oidx] = __builtin_bit_cast(short, h);
            } else if (t < 224) {
                sM[s * 224 + t] = 0;         // K-padding
            }
            float sq = mval * mval;
#pragma unroll
            for (int off = 32; off; off >>= 1) sq += __shfl_down(sq, off, 64);
            if (lane == 0) atomicAdd(&sM2[s], sq);
        }
        // no barrier: ph1(s+1) writes only sH1 / reads sQ; ph3 touches sH2/sM.
        // The s=8 rebuild has its own barrier before ph1 reads the new sQ.
    }
    __syncthreads();

    // ---- cross GEMM: C[k_local][b] = sum_px sM[k][px] * x[b][px] ----
    {
        f32x4 acc = {0.f, 0.f, 0.f, 0.f};
        const short* abase = sM + (lane & 15) * 224 + g * 8;
        const short* bbase = xB + (((v * 4 + w) * 7) * 64 + lane) * 8;
#pragma unroll
        for (int s7 = 0; s7 < 7; ++s7) {
            half8v af = *(const half8v*)(const void*)(abase + s7 * 32);
            half8v bf = *(const half8v*)(const void*)(bbase + s7 * 512);
            acc = __builtin_amdgcn_mfma_f32_16x16x32_f16(af, bf, acc, 0, 0, 0);
        }
        int b = w * 16 + (lane & 15);        // D col = lane&15 -> b-local
        float x2v = x2g[v * 64 + b];
        size_t obase = ((size_t)b * 4096 + k0) * 3 + v;
#pragma unroll
        for (int r = 0; r < 4; ++r) {
            int kk = g * 4 + r;              // D row -> k-local
            out[obase + (size_t)kk * 3] = acc[r] - 0.5f * (sM2[kk] + x2v);
        }
    }
}

extern "C" void kernel_launch(void* const* d_in, const int* in_sizes, int n_in,
                              void* d_out, int out_size, void* d_ws, size_t ws_size,
                              hipStream_t stream) {
    const float* x     = (const float*)d_in[0];
    const float* le    = (const float*)d_in[1];
    const float* lin_w = (const float*)d_in[2];
    const float* lin_b = (const float*)d_in[3];
    const float* w1    = (const float*)d_in[4];
    const float* b1    = (const float*)d_in[5];
    const float* w2    = (const float*)d_in[6];
    const float* b2    = (const float*)d_in[7];
    const float* w3    = (const float*)d_in[8];
    const float* b3    = (const float*)d_in[9];
    float* out = (float*)d_out;

    float* ws = (float*)d_ws;
    // workspace (floats):
    float* x2g  = ws;                        // 192
    short* xB   = (short*)(ws + 192);        // 43008 shorts = 21504 floats
    short* Wf   = (short*)(ws + 21760);      // 13824 shorts = 6912 floats
    float* Qa   = ws + 28736;                // 316800
    float* Qb   = ws + 345536;               // 316800
    float* P3   = ws + 662336;               // 3*33*4096 = 405504

    pmat_kernel<<<dim3(16, 5, 3), 256, 0, stream>>>(le, lin_w, lin_b, P3);
    prep_kernel<<<216, 320, 0, stream>>>(x, P3, w1, b1, w2, Qa, Qb, x2g, xB, Wf);
    fusedgemm_kernel<<<dim3(256, 3), 256, 0, stream>>>(Qa, Qb, Wf, b2, w3, b3,
                                                       xB, x2g, out);
}